// Round 6
// baseline (102.572 us; speedup 1.0000x reference)
//
#include <hip/hip_runtime.h>

// Problem constants (from reference)
#define N_CAM   6
#define N_HEADS 8
#define EMBD    256
#define HS      32
#define L       100     // seq_len = 10*10
#define BS      2
#define CAM_STRIDE (L * EMBD)   // 25600 floats per (b, cam)
#define CK      (N_CAM * L)     // 600 combined (cam, sk) index

// Workspace layout (floats):
//   wsum : 1536*256 = 393216   folded W (sum over 4 ref slots)
//   ktr  : 2*8*32*600 = 307200 [b][h][d][cam*100+sk] transposed K
//   P    : 200*256*4 = 204800  split-K partials, float4 per (row,e): .c = chunk
//   E    : 200*8*100 = 160000  E[b*100+sq][h][sk] (camera-folded exp scores)
#define WS_WSUM 0
#define WS_KTR  (WS_WSUM + 1536 * 256)
#define WS_P    (WS_KTR + 2 * N_HEADS * HS * CK)
#define WS_E    (WS_P + 200 * 256 * 4)

// ---------------------------------------------------------------------------
// L1 (480 blocks) — independent prep jobs (R2/R5-measured structure):
//  blocks [0,96):  transpose feat -> ktr[b][h][d][cam*100+sk]
//  blocks [96,480): fold W_v (1536x1024) over 4 ref slots -> wsum (1536x256)
// ---------------------------------------------------------------------------
__global__ __launch_bounds__(256) void prep_kernel(const float* __restrict__ feat,
                                                   const float4* __restrict__ Wv4,
                                                   float* __restrict__ ws) {
    const int t = threadIdx.x;
    if (blockIdx.x < 96) {
        __shared__ float tile[100 * 33];  // +1 pad: conflict-free column reads
        int blk = blockIdx.x;
        int b   = blk / 48;
        int rem = blk - b * 48;
        int cam = rem >> 3;
        int h   = rem & 7;
        const float* src = feat + (size_t)(b * N_CAM + cam) * CAM_STRIDE + h * HS;
        for (int idx = t; idx < 100 * 32; idx += 256) {
            int sk = idx >> 5;
            int d  = idx & 31;
            tile[sk * 33 + d] = src[sk * EMBD + d];       // 128B-contiguous runs
        }
        __syncthreads();
        float* ktr = ws + WS_KTR;
        for (int idx = t; idx < 100 * 32; idx += 256) {
            int d  = idx / 100;
            int sk = idx - d * 100;
            ktr[((size_t)(b * N_HEADS + h) * HS + d) * CK + cam * L + sk] = tile[sk * 33 + d];
        }
    } else {
        // wsum[i][e] = sum_ref W_v[i][ref*256+e]; 384*256 threads = 1536x64 f4
        int tid = (blockIdx.x - 96) * 256 + t;
        int i  = tid >> 6;
        int e4 = tid & 63;
        const float4* row = Wv4 + (size_t)i * 256;
        float4 a = row[e4];
        float4 b = row[64 + e4];
        float4 c = row[128 + e4];
        float4 d = row[192 + e4];
        float4 o;
        o.x = a.x + b.x + c.x + d.x;
        o.y = a.y + b.y + c.y + d.y;
        o.z = a.z + b.z + c.z + d.z;
        o.w = a.w + b.w + c.w + d.w;
        ((float4*)(ws + WS_WSUM))[(size_t)i * 64 + e4] = o;
    }
}

// ---------------------------------------------------------------------------
// L2 (560 blocks) — GEMM partials + E-compute:
//  blocks [0,160):  split-K GEMM, HIGH-INTENSITY tiles: block = (rg,c,nsel)
//                   rows rg*10..+10, K-chunk c of 384, N-half nsel*128.
//                   W-traffic = 160 x 384x128x4B = 31.5 MB (R5 had 157 MB).
//  blocks [160,560): E[b,sq,h,sk] = sum_cam exp(q.k/sqrt(32)) from ktr,
//                   barrier-free coalesced reads (R2/R5-measured structure).
// ---------------------------------------------------------------------------
__global__ __launch_bounds__(256) void mid_kernel(const float* __restrict__ feat,
                                                  const float* __restrict__ query,
                                                  const float* __restrict__ ws_r,
                                                  float* __restrict__ ws_w) {
    const int t = threadIdx.x;
    if (blockIdx.x < 160) {
        // ---- GEMM branch ----
        __shared__ float a_tile[10 * 384];     // [j][kk], 15.4 KB
        const int blk  = blockIdx.x;
        const int rg   = blk >> 3;             // [0,20)
        const int rem  = blk & 7;
        const int c    = rem >> 1;             // K-chunk [0,4)
        const int nsel = rem & 1;              // N-half
        const int r0   = rg * 10;
        const int k0   = c * 384;
        const int n0   = nsel * 128;

        // stage A: a_tile[j*384+kk] = v_in[r0+j][k0+kk]
        for (int i = t; i < 10 * 384; i += 256) {
            int j  = i / 384;
            int kk = i - j * 384;
            int k  = k0 + kk;
            int cam = k >> 8, e2 = k & 255;
            int row = r0 + j;
            int b = row >= 100;
            int s = row - b * 100;
            a_tile[i] = feat[(size_t)(b * N_CAM + cam) * CAM_STRIDE + s * EMBD + e2];
        }
        __syncthreads();

        const int n  = t & 127;                // column within N-half
        const int jh = t >> 7;                 // row half: rows jh*5..+5
        const int e  = n0 + n;
        float acc[5] = {0.f, 0.f, 0.f, 0.f, 0.f};
        const float* wp = ws_r + WS_WSUM + (size_t)k0 * 256 + e;
        const float* at = a_tile + jh * 5 * 384;
#pragma unroll 8
        for (int kk = 0; kk < 384; ++kk) {
            float w = wp[(size_t)kk * 256];    // coalesced across n
            acc[0] += at[kk] * w;              // LDS wave-broadcast (free)
            acc[1] += at[384 + kk] * w;
            acc[2] += at[768 + kk] * w;
            acc[3] += at[1152 + kk] * w;
            acc[4] += at[1536 + kk] * w;
        }

        float* P = ws_w + WS_P;
#pragma unroll
        for (int r = 0; r < 5; ++r)
            P[((size_t)(r0 + jh * 5 + r) * 256 + e) * 4 + c] = acc[r];
    } else {
        // ---- E branch: block = (b, h, sq-tile of 4) ----
        __shared__ float q_s[4 * 32];
        __shared__ float es[4 * CK];      // exp(scores) 4 sq x 600 ck
        int idx = blockIdx.x - 160;       // [0,400)
        int b   = idx / 200;
        int rem = idx - b * 200;
        int h   = rem / 25;
        int sqt = rem - h * 25;
        int sq0 = sqt * 4;

        if (t < 128)
            q_s[t] = query[(size_t)(b * L + sq0 + (t >> 5)) * EMBD + h * HS + (t & 31)];
        __syncthreads();

        const float scale = 0.17677669529663687f;  // 1/sqrt(32)
        const float* kt = ws_r + WS_KTR + (size_t)(b * N_HEADS + h) * HS * CK;

#pragma unroll
        for (int i = 0; i < 3; ++i) {
            int ck = t + i * 256;
            if (ck < CK) {
                float acc0 = 0.f, acc1 = 0.f, acc2 = 0.f, acc3 = 0.f;
#pragma unroll 8
                for (int d = 0; d < 32; ++d) {
                    float k = kt[(size_t)d * CK + ck];   // coalesced across lanes
                    acc0 += q_s[0 * 32 + d] * k;
                    acc1 += q_s[1 * 32 + d] * k;
                    acc2 += q_s[2 * 32 + d] * k;
                    acc3 += q_s[3 * 32 + d] * k;
                }
                es[0 * CK + ck] = __expf(acc0 * scale);
                es[1 * CK + ck] = __expf(acc1 * scale);
                es[2 * CK + ck] = __expf(acc2 * scale);
                es[3 * CK + ck] = __expf(acc3 * scale);
            }
        }
        __syncthreads();

        // camera fold -> E
        float* E = ws_w + WS_E;
        for (int p = t; p < 4 * L; p += 256) {
            int sj = p / 100, sk = p - sj * 100;
            float e = 0.f;
#pragma unroll
            for (int cam = 0; cam < N_CAM; ++cam)
                e += es[sj * CK + cam * L + sk];
            E[((size_t)(b * L + sq0 + sj) * N_HEADS + h) * L + sk] = e;
        }
    }
}

// ---------------------------------------------------------------------------
// L3 (200 blocks): block = (b, sq).
// out[b,sq,e] = (sum_sk E*(p.x+p.y+p.z+p.w) + sumE*bias_e) * 0.25/sumE
// (one float4 load folds all 4 K-chunks; bias folded via sumE)
// ---------------------------------------------------------------------------
__global__ __launch_bounds__(256) void out_kernel(const float* __restrict__ ws,
                                                  const float* __restrict__ b_v,
                                                  float* __restrict__ out) {
    __shared__ float E_s[N_HEADS * L];    // 800 floats
    const int t  = threadIdx.x;
    const int b  = blockIdx.x / 100;
    const int sq = blockIdx.x - b * 100;

    const float* E = ws + WS_E + (size_t)(b * L + sq) * N_HEADS * L;
    for (int i = t; i < N_HEADS * L; i += 256) E_s[i] = E[i];
    __syncthreads();

    const int h = t >> 5;
    float sumE = 0.f;
#pragma unroll 4
    for (int sk = 0; sk < L; ++sk) sumE += E_s[h * L + sk];   // broadcast reads

    float bias = b_v[t] + b_v[256 + t] + b_v[512 + t] + b_v[768 + t];

    const float4* p4 = (const float4*)(ws + WS_P) + (size_t)b * L * 256 + t;
    float acc = 0.f;
#pragma unroll 8
    for (int sk = 0; sk < L; ++sk) {
        float4 p = p4[(size_t)sk * 256];  // 16B coalesced, folds 4 K-chunks
        acc += E_s[h * L + sk] * (p.x + p.y + p.z + p.w);
    }

    out[(size_t)(b * L + sq) * EMBD + t] = (acc + sumE * bias) * (0.25f / sumE);
}

// ---------------------------------------------------------------------------
extern "C" void kernel_launch(void* const* d_in, const int* in_sizes, int n_in,
                              void* d_out, int out_size, void* d_ws, size_t ws_size,
                              hipStream_t stream) {
    const float* feat  = (const float*)d_in[0];  // (2,1,6,256,10,10)
    const float* query = (const float*)d_in[1];  // (2,100,256)
    const float4* Wv   = (const float4*)d_in[2]; // (1536,1024)
    const float* bv    = (const float*)d_in[3];  // (1024,)
    float* outp = (float*)d_out;                 // (2,100,256)
    float* ws   = (float*)d_ws;

    // L1: ktr transpose + W fold (independent, one launch)
    prep_kernel<<<480, 256, 0, stream>>>(feat, Wv, ws);
    // L2: high-intensity split-K GEMM (160 blk) + E-compute (400 blk)
    mid_kernel<<<560, 256, 0, stream>>>(feat, query, ws, ws);
    // L3: E-weighted reduce + bias + normalize
    out_kernel<<<200, 256, 0, stream>>>(ws, bv, outp);
}

// Round 7
// 93.261 us; speedup vs baseline: 1.0998x; 1.0998x over previous
//
#include <hip/hip_runtime.h>

// Problem constants (from reference)
#define N_CAM   6
#define N_HEADS 8
#define EMBD    256
#define HS      32
#define L       100     // seq_len = 10*10
#define BS      2
#define CAM_STRIDE (L * EMBD)   // 25600 floats per (b, cam)
#define CK      (N_CAM * L)     // 600 combined (cam, sk) index

// Workspace layout (floats):
//   wsum : 1536*256 = 393216   folded W (sum over 4 ref slots)  [L2-resident]
//   ktr  : 2*8*32*600 = 307200 [b][h][d][cam*100+sk] transposed K
//   P    : 200*256*4 = 204800  split-K partials, float4 per (row,e): .c = chunk
//   E    : 200*8*100 = 160000  E[b*100+sq][h][sk] (camera-folded exp scores)
#define WS_WSUM 0
#define WS_KTR  (WS_WSUM + 1536 * 256)
#define WS_P    (WS_KTR + 2 * N_HEADS * HS * CK)
#define WS_E    (WS_P + 200 * 256 * 4)

// ---------------------------------------------------------------------------
// L1 (480 blocks) — independent prep jobs (R2/R5-measured structure):
//  blocks [0,96):  transpose feat -> ktr[b][h][d][cam*100+sk]
//  blocks [96,480): fold W_v (1536x1024) over 4 ref slots -> wsum (1536x256)
// ---------------------------------------------------------------------------
__global__ __launch_bounds__(256) void prep_kernel(const float* __restrict__ feat,
                                                   const float4* __restrict__ Wv4,
                                                   float* __restrict__ ws) {
    const int t = threadIdx.x;
    if (blockIdx.x < 96) {
        __shared__ float tile[100 * 33];  // +1 pad: conflict-free column reads
        int blk = blockIdx.x;
        int b   = blk / 48;
        int rem = blk - b * 48;
        int cam = rem >> 3;
        int h   = rem & 7;
        // f4-vectorized staging: 100 rows x 8 float4 = 800 f4 loads
        const float4* src4 = reinterpret_cast<const float4*>(
            feat + (size_t)(b * N_CAM + cam) * CAM_STRIDE + h * HS);
        for (int idx = t; idx < 100 * 8; idx += 256) {
            int sk = idx >> 3;
            int d4 = idx & 7;
            float4 v = src4[sk * (EMBD / 4) + d4];       // 128B-contiguous runs
            float* dst = &tile[sk * 33 + d4 * 4];
            dst[0] = v.x; dst[1] = v.y; dst[2] = v.z; dst[3] = v.w;
        }
        __syncthreads();
        float* ktr = ws + WS_KTR;
        for (int idx = t; idx < 100 * 32; idx += 256) {
            int d  = idx / 100;
            int sk = idx - d * 100;
            // lanes at fixed d write consecutive sk -> coalesced
            ktr[((size_t)(b * N_HEADS + h) * HS + d) * CK + cam * L + sk] = tile[sk * 33 + d];
        }
    } else {
        // wsum[i][e] = sum_ref W_v[i][ref*256+e]; 384*256 threads = 1536x64 f4
        int tid = (blockIdx.x - 96) * 256 + t;
        int i  = tid >> 6;
        int e4 = tid & 63;
        const float4* row = Wv4 + (size_t)i * 256;
        float4 a = row[e4];
        float4 b = row[64 + e4];
        float4 c = row[128 + e4];
        float4 d = row[192 + e4];
        float4 o;
        o.x = a.x + b.x + c.x + d.x;
        o.y = a.y + b.y + c.y + d.y;
        o.z = a.z + b.z + c.z + d.z;
        o.w = a.w + b.w + c.w + d.w;
        ((float4*)(ws + WS_WSUM))[(size_t)i * 64 + e4] = o;
    }
}

// ---------------------------------------------------------------------------
// L2 (800 blocks) — GEMM partials + E-compute, co-scheduled for TLP
// (R5-measured config: rows=2, c=4 -> min per-wave serial cycles; wsum is
//  L2-resident so the 157 MB re-read is ~4.5 us at L2 BW, not the bottleneck):
//  blocks [0,400):  split-K GEMM. block=(rg,c): rows rg*2..+2, K-chunk c of
//                   384. P packed float4 per (row,e).
//  blocks [400,800): E[b,sq,h,sk] = sum_cam exp(q.k/sqrt(32)) from ktr.
// ---------------------------------------------------------------------------
__global__ __launch_bounds__(256) void mid_kernel(const float* __restrict__ feat,
                                                  const float* __restrict__ query,
                                                  const float* __restrict__ ws_r,
                                                  float* __restrict__ ws_w) {
    const int t = threadIdx.x;
    if (blockIdx.x < 400) {
        // ---- GEMM branch ----
        __shared__ float a_tile[2 * 384];
        const int rg = blockIdx.x >> 2;
        const int c  = blockIdx.x & 3;
        const int r0 = rg * 2;
        const int k0 = c * 384;

        // stage A: a_tile[j*384+kk] = v_in[r0+j][k0+kk]
        for (int i = t; i < 768; i += 256) {
            int j  = i >= 384;
            int kk = i - j * 384;
            int k  = k0 + kk;
            int cam = k >> 8, e2 = k & 255;
            int row = r0 + j;
            int b = row >= 100;
            int s = row - b * 100;
            a_tile[i] = feat[(size_t)(b * N_CAM + cam) * CAM_STRIDE + s * EMBD + e2];
        }
        __syncthreads();

        float acc0 = 0.f, acc1 = 0.f;
        const float* wp = ws_r + WS_WSUM + (size_t)k0 * 256 + t;
#pragma unroll 32
        for (int kk = 0; kk < 384; ++kk) {
            float w = wp[(size_t)kk * 256];   // coalesced across t, L2-hit
            acc0 += a_tile[kk] * w;           // LDS broadcast (free)
            acc1 += a_tile[384 + kk] * w;
        }

        float* P = ws_w + WS_P;
        P[((size_t)(r0 + 0) * 256 + t) * 4 + c] = acc0;
        P[((size_t)(r0 + 1) * 256 + t) * 4 + c] = acc1;
    } else {
        // ---- E branch: block = (b, h, sq-tile of 4) ----
        __shared__ float q_s[4 * 32];
        __shared__ float es[4 * CK];      // exp(scores) 4 sq x 600 ck
        int idx = blockIdx.x - 400;       // [0,400)
        int b   = idx / 200;
        int rem = idx - b * 200;
        int h   = rem / 25;
        int sqt = rem - h * 25;
        int sq0 = sqt * 4;

        if (t < 128)
            q_s[t] = query[(size_t)(b * L + sq0 + (t >> 5)) * EMBD + h * HS + (t & 31)];
        __syncthreads();

        const float scale = 0.17677669529663687f;  // 1/sqrt(32)
        const float* kt = ws_r + WS_KTR + (size_t)(b * N_HEADS + h) * HS * CK;

#pragma unroll
        for (int i = 0; i < 3; ++i) {
            int ck = t + i * 256;
            if (ck < CK) {
                float acc0 = 0.f, acc1 = 0.f, acc2 = 0.f, acc3 = 0.f;
#pragma unroll 8
                for (int d = 0; d < 32; ++d) {
                    float k = kt[(size_t)d * CK + ck];   // coalesced across lanes
                    acc0 += q_s[0 * 32 + d] * k;
                    acc1 += q_s[1 * 32 + d] * k;
                    acc2 += q_s[2 * 32 + d] * k;
                    acc3 += q_s[3 * 32 + d] * k;
                }
                es[0 * CK + ck] = __expf(acc0 * scale);
                es[1 * CK + ck] = __expf(acc1 * scale);
                es[2 * CK + ck] = __expf(acc2 * scale);
                es[3 * CK + ck] = __expf(acc3 * scale);
            }
        }
        __syncthreads();

        // camera fold -> E
        float* E = ws_w + WS_E;
        for (int p = t; p < 4 * L; p += 256) {
            int sj = p / 100, sk = p - sj * 100;
            float e = 0.f;
#pragma unroll
            for (int cam = 0; cam < N_CAM; ++cam)
                e += es[sj * CK + cam * L + sk];
            E[((size_t)(b * L + sq0 + sj) * N_HEADS + h) * L + sk] = e;
        }
    }
}

// ---------------------------------------------------------------------------
// L3 (200 blocks): block = (b, sq).
// out[b,sq,e] = (sum_sk E*(p.x+p.y+p.z+p.w) + sumE*bias_e) * 0.25/sumE
// (one float4 load folds all 4 K-chunks; bias folded via sumE)
// ---------------------------------------------------------------------------
__global__ __launch_bounds__(256) void out_kernel(const float* __restrict__ ws,
                                                  const float* __restrict__ b_v,
                                                  float* __restrict__ out) {
    __shared__ float E_s[N_HEADS * L];    // 800 floats
    const int t  = threadIdx.x;
    const int b  = blockIdx.x / 100;
    const int sq = blockIdx.x - b * 100;

    const float* E = ws + WS_E + (size_t)(b * L + sq) * N_HEADS * L;
    for (int i = t; i < N_HEADS * L; i += 256) E_s[i] = E[i];
    __syncthreads();

    const int h = t >> 5;
    float sumE = 0.f;
#pragma unroll 4
    for (int sk = 0; sk < L; ++sk) sumE += E_s[h * L + sk];   // broadcast reads

    float bias = b_v[t] + b_v[256 + t] + b_v[512 + t] + b_v[768 + t];

    const float4* p4 = (const float4*)(ws + WS_P) + (size_t)b * L * 256 + t;
    float acc = 0.f;
#pragma unroll 8
    for (int sk = 0; sk < L; ++sk) {
        float4 p = p4[(size_t)sk * 256];  // 16B coalesced, folds 4 K-chunks
        acc += E_s[h * L + sk] * (p.x + p.y + p.z + p.w);
    }

    out[(size_t)(b * L + sq) * EMBD + t] = (acc + sumE * bias) * (0.25f / sumE);
}

// ---------------------------------------------------------------------------
extern "C" void kernel_launch(void* const* d_in, const int* in_sizes, int n_in,
                              void* d_out, int out_size, void* d_ws, size_t ws_size,
                              hipStream_t stream) {
    const float* feat  = (const float*)d_in[0];  // (2,1,6,256,10,10)
    const float* query = (const float*)d_in[1];  // (2,100,256)
    const float4* Wv   = (const float4*)d_in[2]; // (1536,1024)
    const float* bv    = (const float*)d_in[3];  // (1024,)
    float* outp = (float*)d_out;                 // (2,100,256)
    float* ws   = (float*)d_ws;

    // L1: ktr transpose + W fold (independent, one launch)
    prep_kernel<<<480, 256, 0, stream>>>(feat, Wv, ws);
    // L2: split-K GEMM (400 blk, R5 config) + E-compute (400 blk)
    mid_kernel<<<800, 256, 0, stream>>>(feat, query, ws, ws);
    // L3: E-weighted reduce + bias + normalize
    out_kernel<<<200, 256, 0, stream>>>(ws, bv, outp);
}

// Round 8
// 90.373 us; speedup vs baseline: 1.1350x; 1.0320x over previous
//
#include <hip/hip_runtime.h>

// Problem constants (from reference)
#define N_CAM   6
#define N_HEADS 8
#define EMBD    256
#define HS      32
#define L       100     // seq_len = 10*10
#define BS      2
#define CAM_STRIDE (L * EMBD)   // 25600 floats per (b, cam)
#define CK      (N_CAM * L)     // 600 combined (cam, sk) index

// Workspace layout (floats):
//   wsum : 1536*256 = 393216   folded W (sum over 4 ref slots)  [L2-resident]
//   ktr  : 2*8*8*600 float4 = 307200 floats  [b][h][d4][ck] float4-packed K
//   P    : 200*256*4 = 204800  split-K partials, float4 per (row,e): .c = chunk
//   E    : 200*8*100 = 160000  E[b*100+sq][h][sk] (camera-folded exp scores)
#define WS_WSUM 0
#define WS_KTR  (WS_WSUM + 1536 * 256)
#define WS_P    (WS_KTR + 2 * N_HEADS * 8 * CK * 4)
#define WS_E    (WS_P + 200 * 256 * 4)

// ---------------------------------------------------------------------------
// L1 (480 blocks) — independent prep jobs (R2/R5/R7-measured structure):
//  blocks [0,96):  transpose feat -> ktr4[b][h][d4][cam*100+sk] (float4 over d)
//  blocks [96,480): fold W_v (1536x1024) over 4 ref slots -> wsum (1536x256)
// ---------------------------------------------------------------------------
__global__ __launch_bounds__(256) void prep_kernel(const float* __restrict__ feat,
                                                   const float4* __restrict__ Wv4,
                                                   float* __restrict__ ws) {
    const int t = threadIdx.x;
    if (blockIdx.x < 96) {
        __shared__ float tile[100 * 33];  // +1 pad: conflict-free column reads
        int blk = blockIdx.x;
        int b   = blk / 48;
        int rem = blk - b * 48;
        int cam = rem >> 3;
        int h   = rem & 7;
        // f4-vectorized staging: 100 rows x 8 float4 = 800 f4 loads
        const float4* src4 = reinterpret_cast<const float4*>(
            feat + (size_t)(b * N_CAM + cam) * CAM_STRIDE + h * HS);
        for (int idx = t; idx < 100 * 8; idx += 256) {
            int sk = idx >> 3;
            int d4 = idx & 7;
            float4 v = src4[sk * (EMBD / 4) + d4];       // 128B-contiguous runs
            float* dst = &tile[sk * 33 + d4 * 4];
            dst[0] = v.x; dst[1] = v.y; dst[2] = v.z; dst[3] = v.w;
        }
        __syncthreads();
        // write float4-packed ktr: [b][h][d4][cam*100+sk]
        float4* ktr4 = reinterpret_cast<float4*>(ws + WS_KTR)
                     + (size_t)(b * N_HEADS + h) * 8 * CK + cam * L;
        for (int idx = t; idx < 8 * 100; idx += 256) {
            int d4 = idx / 100;
            int sk = idx - d4 * 100;
            const float* s = &tile[sk * 33 + d4 * 4];    // banks cycle (33%32==1)
            // consecutive lanes -> consecutive sk -> coalesced 16B/lane writes
            ktr4[(size_t)d4 * CK + sk] = make_float4(s[0], s[1], s[2], s[3]);
        }
    } else {
        // wsum[i][e] = sum_ref W_v[i][ref*256+e]; 384*256 threads = 1536x64 f4
        int tid = (blockIdx.x - 96) * 256 + t;
        int i  = tid >> 6;
        int e4 = tid & 63;
        const float4* row = Wv4 + (size_t)i * 256;
        float4 a = row[e4];
        float4 b = row[64 + e4];
        float4 c = row[128 + e4];
        float4 d = row[192 + e4];
        float4 o;
        o.x = a.x + b.x + c.x + d.x;
        o.y = a.y + b.y + c.y + d.y;
        o.z = a.z + b.z + c.z + d.z;
        o.w = a.w + b.w + c.w + d.w;
        ((float4*)(ws + WS_WSUM))[(size_t)i * 64 + e4] = o;
    }
}

// ---------------------------------------------------------------------------
// L2 (800 blocks) — GEMM partials + E-compute, co-scheduled for TLP:
//  blocks [0,400):  split-K GEMM (R5/R7 config, byte-identical): block=(rg,c),
//                   rows rg*2..+2, K-chunk c of 384. P packed float4/(row,e).
//  blocks [400,800): E from float4-packed ktr: 24 dwordx4 loads per thread
//                   (was 96 scalar dword loads), 16B/lane coalesced.
// ---------------------------------------------------------------------------
__global__ __launch_bounds__(256) void mid_kernel(const float* __restrict__ feat,
                                                  const float* __restrict__ query,
                                                  const float* __restrict__ ws_r,
                                                  float* __restrict__ ws_w) {
    const int t = threadIdx.x;
    if (blockIdx.x < 400) {
        // ---- GEMM branch (unchanged from R5/R7) ----
        __shared__ float a_tile[2 * 384];
        const int rg = blockIdx.x >> 2;
        const int c  = blockIdx.x & 3;
        const int r0 = rg * 2;
        const int k0 = c * 384;

        for (int i = t; i < 768; i += 256) {
            int j  = i >= 384;
            int kk = i - j * 384;
            int k  = k0 + kk;
            int cam = k >> 8, e2 = k & 255;
            int row = r0 + j;
            int b = row >= 100;
            int s = row - b * 100;
            a_tile[i] = feat[(size_t)(b * N_CAM + cam) * CAM_STRIDE + s * EMBD + e2];
        }
        __syncthreads();

        float acc0 = 0.f, acc1 = 0.f;
        const float* wp = ws_r + WS_WSUM + (size_t)k0 * 256 + t;
#pragma unroll 32
        for (int kk = 0; kk < 384; ++kk) {
            float w = wp[(size_t)kk * 256];   // coalesced across t, L2-hit
            acc0 += a_tile[kk] * w;           // LDS broadcast (free)
            acc1 += a_tile[384 + kk] * w;
        }

        float* P = ws_w + WS_P;
        P[((size_t)(r0 + 0) * 256 + t) * 4 + c] = acc0;
        P[((size_t)(r0 + 1) * 256 + t) * 4 + c] = acc1;
    } else {
        // ---- E branch: block = (b, h, sq-tile of 4) ----
        __shared__ float q_s[4 * 32];
        __shared__ float es[4 * CK];      // exp(scores) 4 sq x 600 ck
        int idx = blockIdx.x - 400;       // [0,400)
        int b   = idx / 200;
        int rem = idx - b * 200;
        int h   = rem / 25;
        int sqt = rem - h * 25;
        int sq0 = sqt * 4;

        if (t < 128)
            q_s[t] = query[(size_t)(b * L + sq0 + (t >> 5)) * EMBD + h * HS + (t & 31)];
        __syncthreads();

        const float scale = 0.17677669529663687f;  // 1/sqrt(32)
        const float4* kt4 = reinterpret_cast<const float4*>(ws_r + WS_KTR)
                          + (size_t)(b * N_HEADS + h) * 8 * CK;

#pragma unroll
        for (int i = 0; i < 3; ++i) {
            int ck = t + i * 256;
            if (ck < CK) {
                float acc0 = 0.f, acc1 = 0.f, acc2 = 0.f, acc3 = 0.f;
#pragma unroll
                for (int d4 = 0; d4 < 8; ++d4) {
                    float4 kv = kt4[(size_t)d4 * CK + ck];   // 16B/lane coalesced
                    const float* q0 = &q_s[0 * 32 + d4 * 4];
                    const float* q1 = &q_s[1 * 32 + d4 * 4];
                    const float* q2 = &q_s[2 * 32 + d4 * 4];
                    const float* q3 = &q_s[3 * 32 + d4 * 4];
                    acc0 += q0[0] * kv.x + q0[1] * kv.y + q0[2] * kv.z + q0[3] * kv.w;
                    acc1 += q1[0] * kv.x + q1[1] * kv.y + q1[2] * kv.z + q1[3] * kv.w;
                    acc2 += q2[0] * kv.x + q2[1] * kv.y + q2[2] * kv.z + q2[3] * kv.w;
                    acc3 += q3[0] * kv.x + q3[1] * kv.y + q3[2] * kv.z + q3[3] * kv.w;
                }
                es[0 * CK + ck] = __expf(acc0 * scale);
                es[1 * CK + ck] = __expf(acc1 * scale);
                es[2 * CK + ck] = __expf(acc2 * scale);
                es[3 * CK + ck] = __expf(acc3 * scale);
            }
        }
        __syncthreads();

        // camera fold -> E
        float* E = ws_w + WS_E;
        for (int p = t; p < 4 * L; p += 256) {
            int sj = p / 100, sk = p - sj * 100;
            float e = 0.f;
#pragma unroll
            for (int cam = 0; cam < N_CAM; ++cam)
                e += es[sj * CK + cam * L + sk];
            E[((size_t)(b * L + sq0 + sj) * N_HEADS + h) * L + sk] = e;
        }
    }
}

// ---------------------------------------------------------------------------
// L3 (200 blocks): block = (b, sq).
// out[b,sq,e] = (sum_sk E*(p.x+p.y+p.z+p.w) + sumE*bias_e) * 0.25/sumE
// ---------------------------------------------------------------------------
__global__ __launch_bounds__(256) void out_kernel(const float* __restrict__ ws,
                                                  const float* __restrict__ b_v,
                                                  float* __restrict__ out) {
    __shared__ float E_s[N_HEADS * L];    // 800 floats
    const int t  = threadIdx.x;
    const int b  = blockIdx.x / 100;
    const int sq = blockIdx.x - b * 100;

    const float* E = ws + WS_E + (size_t)(b * L + sq) * N_HEADS * L;
    for (int i = t; i < N_HEADS * L; i += 256) E_s[i] = E[i];
    __syncthreads();

    const int h = t >> 5;
    float sumE = 0.f;
#pragma unroll 4
    for (int sk = 0; sk < L; ++sk) sumE += E_s[h * L + sk];   // broadcast reads

    float bias = b_v[t] + b_v[256 + t] + b_v[512 + t] + b_v[768 + t];

    const float4* p4 = (const float4*)(ws + WS_P) + (size_t)b * L * 256 + t;
    float acc = 0.f;
#pragma unroll 16
    for (int sk = 0; sk < L; ++sk) {
        float4 p = p4[(size_t)sk * 256];  // 16B coalesced, folds 4 K-chunks
        acc += E_s[h * L + sk] * (p.x + p.y + p.z + p.w);
    }

    out[(size_t)(b * L + sq) * EMBD + t] = (acc + sumE * bias) * (0.25f / sumE);
}

// ---------------------------------------------------------------------------
extern "C" void kernel_launch(void* const* d_in, const int* in_sizes, int n_in,
                              void* d_out, int out_size, void* d_ws, size_t ws_size,
                              hipStream_t stream) {
    const float* feat  = (const float*)d_in[0];  // (2,1,6,256,10,10)
    const float* query = (const float*)d_in[1];  // (2,100,256)
    const float4* Wv   = (const float4*)d_in[2]; // (1536,1024)
    const float* bv    = (const float*)d_in[3];  // (1024,)
    float* outp = (float*)d_out;                 // (2,100,256)
    float* ws   = (float*)d_ws;

    // L1: float4-packed ktr transpose + W fold (independent, one launch)
    prep_kernel<<<480, 256, 0, stream>>>(feat, Wv, ws);
    // L2: split-K GEMM (400 blk, R5/R7 config) + float4 E-compute (400 blk)
    mid_kernel<<<800, 256, 0, stream>>>(feat, query, ws, ws);
    // L3: E-weighted reduce + bias + normalize
    out_kernel<<<200, 256, 0, stream>>>(ws, bv, outp);
}